// Round 3
// baseline (264.164 us; speedup 1.0000x reference)
//
#include <hip/hip_runtime.h>

typedef _Float16 half_t;
typedef __attribute__((ext_vector_type(4))) _Float16 half4;
typedef __attribute__((ext_vector_type(8))) _Float16 half8;
typedef __attribute__((ext_vector_type(4))) float floatx4;

#define MFMA_F16(A,B,C)  __builtin_amdgcn_mfma_f32_16x16x32_f16(A,B,C,0,0,0)

typedef __attribute__((address_space(1))) const void gvoid_t;
typedef __attribute__((address_space(3))) void svoid_t;

// async global->LDS, 16B per lane, dest = wave-uniform base + lane*16
__device__ __forceinline__ void async_copy16(const half_t* g, half_t* l) {
    __builtin_amdgcn_global_load_lds((gvoid_t*)g, (svoid_t*)l, 16, 0, 0);
}

// ============================================================================
// Prep: x fp32 -> fp16 (xh); w_qkv, w_proj fp32 -> fp16 TRANSPOSED.
// blocks: [0,6144) x-convert; [6144,6576) w_qkv 64x64 tiles; [6576,6720) w_proj
// ============================================================================
__global__ __launch_bounds__(256)
void prep_kernel(const float* __restrict__ x, const float* __restrict__ w_qkv,
                 const float* __restrict__ w_proj, half_t* __restrict__ xh,
                 half_t* __restrict__ wqkvT, half_t* __restrict__ wprojT)
{
    __shared__ half_t tile[64 * 65];
    const int id = blockIdx.x, tid = threadIdx.x;
    if (id < 6144) {
        size_t e = (size_t)id * 1024 + tid * 4;
        float4 f = *(const float4*)(x + e);
        half4 h = { (half_t)f.x, (half_t)f.y, (half_t)f.z, (half_t)f.w };
        *(half4*)(xh + e) = h;
        return;
    }
    const float* src; half_t* dst; int lds, tr0, tc0;
    if (id < 6576) { int t = id - 6144; src = w_qkv; dst = wqkvT; lds = 2304;
                     tr0 = (t / 36) * 64; tc0 = (t % 36) * 64; }
    else           { int t = id - 6576; src = w_proj; dst = wprojT; lds = 768;
                     tr0 = (t / 12) * 64; tc0 = (t % 12) * 64; }
    #pragma unroll
    for (int i = 0; i < 4; i++) {
        int e = tid + i * 256, r = e >> 4, c4 = (e & 15) << 2;
        float4 f = *(const float4*)(src + (size_t)(tr0 + r) * lds + tc0 + c4);
        tile[(c4 + 0) * 65 + r] = (half_t)f.x;
        tile[(c4 + 1) * 65 + r] = (half_t)f.y;
        tile[(c4 + 2) * 65 + r] = (half_t)f.z;
        tile[(c4 + 3) * 65 + r] = (half_t)f.w;
    }
    __syncthreads();
    #pragma unroll
    for (int i = 0; i < 4; i++) {
        int e = tid + i * 256, c = e >> 4, r4 = (e & 15) << 2;
        half4 h = { tile[c * 65 + r4], tile[c * 65 + r4 + 1],
                    tile[c * 65 + r4 + 2], tile[c * 65 + r4 + 3] };
        *(half4*)(dst + (size_t)(tc0 + c) * 768 + tr0 + r4) = h;
    }
}

// MFMA accumulate helpers (static indexing throughout)
#define MMAC46(SA, SB)                                                     \
    do {                                                                   \
        _Pragma("unroll") for (int mi = 0; mi < 4; mi++)                   \
        _Pragma("unroll") for (int ni = 0; ni < 6; ni++)                   \
            acc[mi][ni] = MFMA_F16(SA[mi], SB[ni], acc[mi][ni]);           \
    } while (0)

#define MMAC44(SA, SB)                                                     \
    do {                                                                   \
        _Pragma("unroll") for (int mi = 0; mi < 4; mi++)                   \
        _Pragma("unroll") for (int ni = 0; ni < 4; ni++)                   \
            acc[mi][ni] = MFMA_F16(SA[mi], SB[ni], acc[mi][ni]);           \
    } while (0)

// ============================================================================
// QKV GEMM v4: NO-LDS streaming MFMA. Theory: all LDS-staged variants
// (r0/r1/r2) are global_load_lds DMA-instruction-throughput bound (~85cy per
// wave-DMA-instr per CU: 368K instrs total == 51us measured; MfmaUtil tracks
// MFMA:DMA ratio across r0/r1/r2/m97). Fix: load MFMA fragments DIRECTLY
// from global to VGPR (lane(l16,quad) -> A[row=l16][k=quad*8..+8] = 16 rows x
// 64B coalesced dwordx4, L1/L2-resident), register-double-buffered, K fully
// unrolled (k-chunk offset kc*64B fits the 13-bit imm), ZERO barriers.
// 128(M) x 192(N) per block (4 waves, per-wave 64x96 = 4x6 frags), grid
// 64x12 = 768, XCD swizzle keeps m-strip -> fixed XCD (A panels L2-local).
// Epilogue contracts unchanged (q->qT scaled, k->[tok][d], v->vT' permuted).
// ============================================================================
__global__ __launch_bounds__(256, 2)
void gemm_qkv(const half_t* __restrict__ A, const half_t* __restrict__ Bt,
              half_t* __restrict__ q_ws, half_t* __restrict__ k_ws,
              half_t* __restrict__ v_ws)
{
    const int lin  = blockIdx.x;                  // 0..767
    const int xcd  = lin & 7, rest = lin >> 3;    // rest 0..95
    const int m0 = ((rest / 12) * 8 + xcd) * 128; // m-strip -> fixed XCD
    const int n0 = (rest % 12) * 192;

    const int tid  = threadIdx.x;
    const int lane = tid & 63;
    const int w    = tid >> 6;                    // 0..3
    const int wm   = w >> 1, wn = w & 1;
    const int quad = lane >> 4, l16 = lane & 15;

    // per-lane fragment base pointers; frag mi/ni adds mi*16 rows = 12288 halfs
    const half_t* Abase = A  + (size_t)(m0 + wm * 64 + l16) * 768 + quad * 8;
    const half_t* Bbase = Bt + (size_t)(n0 + wn * 96 + l16) * 768 + quad * 8;

    floatx4 acc[4][6];
    #pragma unroll
    for (int i = 0; i < 4; i++)
        #pragma unroll
        for (int j = 0; j < 6; j++) acc[i][j] = (floatx4)0.0f;

    #define LDX46(SA, SB, KC)                                                  \
        do {                                                                   \
            _Pragma("unroll") for (int mi = 0; mi < 4; mi++)                   \
                SA[mi] = *(const half8*)(Abase + (size_t)mi * 12288 + (KC) * 32); \
            _Pragma("unroll") for (int ni = 0; ni < 6; ni++)                   \
                SB[ni] = *(const half8*)(Bbase + (size_t)ni * 12288 + (KC) * 32); \
        } while (0)

    half8 aX[4], bX[6], aY[4], bY[6];
    LDX46(aX, bX, 0);
    #pragma unroll
    for (int t = 0; t < 12; ++t) {
        LDX46(aY, bY, 2 * t + 1);
        MMAC46(aX, bX);
        if (t < 11) LDX46(aX, bX, 2 * t + 2);
        MMAC46(aY, bY);
    }
    #undef LDX46

    // epilogue (C layout: col = l16, row = quad*4 + reg).
    // global col = n0 + wn*96 + ni*16 + l16; 192 | 768 -> sel uniform/block.
    const int sel  = (n0 >= 1536) ? 2 : (n0 >= 768 ? 1 : 0);
    const int rem0 = n0 - sel * 768;
    const int bb   = m0 >> 10;
    const int t0   = m0 & 1023;             // block's tok base (128-aligned)
    const int rw   = wm * 64;

    if (sel == 0) {                         // q -> qT[d][tok], scaled, half4
        #pragma unroll
        for (int mi = 0; mi < 4; mi++)
            #pragma unroll
            for (int ni = 0; ni < 6; ni++) {
                int cb = rem0 + wn*96 + ni*16;
                int hh = cb >> 6;
                int d  = (cb & 63) + l16;
                size_t base = (size_t)(bb * 12 + hh) * 65536;
                int tok = t0 + rw + mi*16 + quad*4;
                half4 hv = { (half_t)(acc[mi][ni][0] * 0.125f),
                             (half_t)(acc[mi][ni][1] * 0.125f),
                             (half_t)(acc[mi][ni][2] * 0.125f),
                             (half_t)(acc[mi][ni][3] * 0.125f) };
                *(half4*)(q_ws + base + (size_t)d * 1024 + tok) = hv;
            }
    } else if (sel == 1) {                  // k -> [tok][d], scalar
        #pragma unroll
        for (int mi = 0; mi < 4; mi++)
            #pragma unroll
            for (int ni = 0; ni < 6; ni++) {
                int cb = rem0 + wn*96 + ni*16;
                int hh = cb >> 6;
                int d  = (cb & 63) + l16;
                size_t base = (size_t)(bb * 12 + hh) * 65536;
                #pragma unroll
                for (int r = 0; r < 4; r++) {
                    int tok = t0 + rw + mi*16 + quad*4 + r;
                    k_ws[base + (size_t)tok * 64 + d] = (half_t)acc[mi][ni][r];
                }
            }
    } else {                                // v -> vT'[d][tokp], half4
        #pragma unroll
        for (int mi = 0; mi < 4; mi++)
            #pragma unroll
            for (int ni = 0; ni < 6; ni++) {
                int cb = rem0 + wn*96 + ni*16;
                int hh = cb >> 6;
                int d  = (cb & 63) + l16;
                size_t base = (size_t)(bb * 12 + hh) * 65536;
                int tokb = t0 + rw + (mi >> 1) * 32;
                int tokp = tokb | (quad << 3) | ((mi & 1) << 2);
                half4 hv = { (half_t)acc[mi][ni][0], (half_t)acc[mi][ni][1],
                             (half_t)acc[mi][ni][2], (half_t)acc[mi][ni][3] };
                *(half4*)(v_ws + base + (size_t)d * 1024 + tokp) = hv;
            }
    }
}

// ============================================================================
// Proj GEMM v2: NO-LDS streaming MFMA, same rationale as gemm_qkv v4.
// 128(M) x 192(N) per block (4 waves, 64x96/wave), grid = 64 strips x 4
// n-cols = 256 blocks = EXACTLY 1/CU (perfect balance). Register
// triple-buffered (1 wave/SIMD -> need 2-step prefetch distance to cover
// L2 latency). Epilogue: per-wave LDS transpose scratch (rows padded to
// 100 f32 -> 2 lanes/bank, 16B-aligned) -> float4 stores.
// ============================================================================
__global__ __launch_bounds__(256, 2)
void gemm_proj(const half_t* __restrict__ A, const half_t* __restrict__ Bt,
               float* __restrict__ Cout, const float* __restrict__ bias)
{
    __shared__ float escr[4][1600];

    const int lin  = blockIdx.x;                 // 0..255
    const int xcd  = lin & 7, rest = lin >> 3;   // rest 0..31
    const int m0 = ((rest / 4) * 8 + xcd) * 128; // m-strip -> fixed XCD
    const int n0 = (rest % 4) * 192;

    const int tid  = threadIdx.x;
    const int lane = tid & 63;
    const int w    = tid >> 6;
    const int wm   = w >> 1, wn = w & 1;
    const int quad = lane >> 4, l16 = lane & 15;

    const half_t* Abase = A  + (size_t)(m0 + wm * 64 + l16) * 768 + quad * 8;
    const half_t* Bbase = Bt + (size_t)(n0 + wn * 96 + l16) * 768 + quad * 8;

    floatx4 acc[4][6];
    #pragma unroll
    for (int i = 0; i < 4; i++)
        #pragma unroll
        for (int j = 0; j < 6; j++) acc[i][j] = (floatx4)0.0f;

    #define LDP(SA, SB, KC)                                                    \
        do {                                                                   \
            _Pragma("unroll") for (int mi = 0; mi < 4; mi++)                   \
                SA[mi] = *(const half8*)(Abase + (size_t)mi * 12288 + (KC) * 32); \
            _Pragma("unroll") for (int ni = 0; ni < 6; ni++)                   \
                SB[ni] = *(const half8*)(Bbase + (size_t)ni * 12288 + (KC) * 32); \
        } while (0)

    half8 aX[4], bX[6], aY[4], bY[6], aZ[4], bZ[6];
    LDP(aX, bX, 0);
    LDP(aY, bY, 1);
    #pragma unroll
    for (int t = 0; t < 8; ++t) {
        LDP(aZ, bZ, 3 * t + 2);
        MMAC46(aX, bX);
        if (3 * t + 3 < 24) LDP(aX, bX, 3 * t + 3);
        MMAC46(aY, bY);
        if (3 * t + 4 < 24) LDP(aY, bY, 3 * t + 4);
        MMAC46(aZ, bZ);
    }
    #undef LDP

    // epilogue: per-wave LDS transpose (rows padded to 100 f32: 400B,
    // 16B-aligned; lane stride 100 -> 2 lanes/bank = conflict-free)
    float bias_v[6];
    #pragma unroll
    for (int ni = 0; ni < 6; ni++)
        bias_v[ni] = bias[n0 + wn * 96 + ni * 16 + l16];
    float* scratch = escr[w];
    #pragma unroll
    for (int mi = 0; mi < 4; mi++) {
        #pragma unroll
        for (int ni = 0; ni < 6; ni++)
            #pragma unroll
            for (int r = 0; r < 4; r++)
                scratch[(quad * 4 + r) * 100 + ni * 16 + l16] =
                    acc[mi][ni][r] + bias_v[ni];
        #pragma unroll
        for (int i = 0; i < 6; i++) {
            int f = quad + i * 4;           // float4 index 0..23 (96 cols)
            float4 v4 = *(const float4*)(scratch + l16 * 100 + f * 4);
            int gm = m0 + wm * 64 + mi * 16 + l16;
            *(float4*)(Cout + (size_t)gm * 768 + n0 + wn * 96 + f * 4) = v4;
        }
    }
}

// ============================================================================
// Flash attention v5: S^T = K.Q^T -> P in registers in PV-A layout; vT'
// key-permuted -> full-rate 16x16x32 PV. Q arrives TRANSPOSED (qT[d][tok])
// -> staged via global_load_lds into Qs, frags built by one-time scalar
// ds_reads. XCD swizzle; K/V double-buffered; no max subtraction.
// LDS: 16+16+16 KB = 48 KB -> 3 blocks/CU.
// ============================================================================
__global__ __launch_bounds__(256, 3)
void attn_kernel(const half_t* __restrict__ qT, const half_t* __restrict__ k,
                 const half_t* __restrict__ vT, half_t* __restrict__ a_ws)
{
    __shared__ __align__(16) half_t Kb[2][4096];
    __shared__ __align__(16) half_t Vb[2][4096];
    __shared__ __align__(16) half_t Qs[64 * 128];

    const int lin  = blockIdx.x;
    const int xcd  = lin & 7, rest = lin >> 3;
    const int qc   = rest & 7;                    // 0..7 (128-row q chunk)
    const int bh   = (rest >> 3) * 8 + xcd;       // 0..95; same bh -> same XCD

    const int tid  = threadIdx.x;
    const int lane = tid & 63;
    const int w    = tid >> 6;
    const int quad = lane >> 4, l16 = lane & 15;

    const half_t* qg = qT + (size_t)bh * 65536;   // [d][tok]
    const half_t* kg = k  + (size_t)bh * 65536;   // [key][d]
    const half_t* vg = vT + (size_t)bh * 65536;   // [d][tok'] permuted

    const int srow = lane >> 3;              // 0..7
    const int sch  = (lane & 7) ^ srow;      // swizzled chunk for deposit

    // stage Q^T tile [64 d][128 toks] (rows of 128, no swizzle: scalar reads)
    #pragma unroll
    for (int j = 0; j < 4; j++) {
        int d0 = w * 16 + j * 4;
        async_copy16(qg + (size_t)(d0 + (lane >> 4)) * 1024 + qc * 128 + (lane & 15) * 8,
                     &Qs[d0 * 128]);
    }
    // prologue prefetch: K/V tile 0 -> buffer 0
    #pragma unroll
    for (int j = 0; j < 2; j++) {
        int row = j * 32 + w * 8;
        async_copy16(kg + (size_t)(row + srow) * 64 + sch * 8, &Kb[0][row * 64]);
        async_copy16(vg + (size_t)(row + srow) * 1024 + sch * 8, &Vb[0][row * 64]);
    }
    __syncthreads();   // drains Q stage (and tile 0)

    // Q fragments (B-operand of S^T MFMA): B[n=query l16][k=d quad*8+j]
    half8 qf[2][2];
    #pragma unroll
    for (int T = 0; T < 2; T++)
        #pragma unroll
        for (int ks = 0; ks < 2; ks++)
            #pragma unroll
            for (int j = 0; j < 8; j++)
                qf[T][ks][j] = Qs[(ks * 32 + quad * 8 + j) * 128
                                  + T * 64 + w * 16 + l16];

    floatx4 acc_o[2][4];
    floatx4 lacc[2];
    #pragma unroll
    for (int T = 0; T < 2; T++) {
        lacc[T] = (floatx4)0.0f;
        #pragma unroll
        for (int dt = 0; dt < 4; dt++) acc_o[T][dt] = (floatx4)0.0f;
    }

    const int xsw = l16 & 7;
    const half8 vone = { (half_t)1.0f, (half_t)1.0f, (half_t)1.0f, (half_t)1.0f,
                         (half_t)1.0f, (half_t)1.0f, (half_t)1.0f, (half_t)1.0f };

    for (int kt = 0; kt < 16; kt++) {
        const int cb = kt & 1;
        __syncthreads();               // drains prefetch of tile kt
        if (kt < 15) {                 // prefetch tile kt+1 into other buffer
            #pragma unroll
            for (int j = 0; j < 2; j++) {
                int row = j * 32 + w * 8;
                async_copy16(kg + (size_t)((kt + 1) * 64 + row + srow) * 64 + sch * 8,
                             &Kb[cb ^ 1][row * 64]);
                async_copy16(vg + (size_t)(row + srow) * 1024 + (kt + 1) * 64 + sch * 8,
                             &Vb[cb ^ 1][row * 64]);
            }
        }
        const half_t* Kc = Kb[cb];
        const half_t* Vc = Vb[cb];

        // S^T = K . Q^T : A-frag = K[key=l16][d=quad*8+j] (LDS), B-frag = qf.
        // C: lane holds S[query=l16][key = mt*16 + quad*4 + r].
        floatx4 sc[2][4];
        #pragma unroll
        for (int T = 0; T < 2; T++)
            #pragma unroll
            for (int mt = 0; mt < 4; mt++) sc[T][mt] = (floatx4)0.0f;
        #pragma unroll
        for (int ks = 0; ks < 2; ks++)
            #pragma unroll
            for (int mt = 0; mt < 4; mt++) {
                half8 kf = *(const half8*)(Kc + (mt * 16 + l16) * 64
                                              + (((ks << 2) + quad) ^ xsw) * 8);
                sc[0][mt] = MFMA_F16(kf, qf[0][ks], sc[0][mt]);
                sc[1][mt] = MFMA_F16(kf, qf[1][ks], sc[1][mt]);
            }

        // P = exp(S), packed per 32-key group into 16x16x32 A-frags
        half8 pa[2][2];   // [T][group]
        #pragma unroll
        for (int T = 0; T < 2; T++)
            #pragma unroll
            for (int g = 0; g < 2; g++) {
                half8 ph;
                #pragma unroll
                for (int r = 0; r < 4; r++) ph[r]     = (half_t)__expf(sc[T][2 * g][r]);
                #pragma unroll
                for (int r = 0; r < 4; r++) ph[4 + r] = (half_t)__expf(sc[T][2 * g + 1][r]);
                pa[T][g] = ph;
            }

        // l += P.1 and O += P.V' (full-rate 16x16x32, b128 V reads)
        #pragma unroll
        for (int g = 0; g < 2; g++) {
            lacc[0] = MFMA_F16(pa[0][g], vone, lacc[0]);
            lacc[1] = MFMA_F16(pa[1][g], vone, lacc[1]);
            #pragma unroll
            for (int dt = 0; dt < 4; dt++) {
                half8 vb = *(const half8*)(Vc + (dt * 16 + l16) * 64
                                              + ((((g << 2) + quad) ^ xsw) << 3));
                acc_o[0][dt] = MFMA_F16(pa[0][g], vb, acc_o[0][dt]);
                acc_o[1][dt] = MFMA_F16(pa[1][g], vb, acc_o[1][dt]);
            }
        }
    }

    // epilogue: a_ws[(b*1024+n)*768 + h*64 + d]; O C-layout row=query quad*4+r
    const int b = bh / 12, h = bh - (bh / 12) * 12;
    #pragma unroll
    for (int T = 0; T < 2; T++)
        #pragma unroll
        for (int r = 0; r < 4; r++) {
            float inv = 1.0f / lacc[T][r];
            int n = qc * 128 + T * 64 + w * 16 + quad * 4 + r;
            half_t* op = a_ws + ((size_t)(b * 1024 + n)) * 768 + h * 64;
            #pragma unroll
            for (int dt = 0; dt < 4; dt++)
                op[dt * 16 + l16] = (half_t)(acc_o[T][dt][r] * inv);
        }
}

extern "C" void kernel_launch(void* const* d_in, const int* in_sizes, int n_in,
                              void* d_out, int out_size, void* d_ws, size_t ws_size,
                              hipStream_t stream)
{
    (void)in_sizes; (void)n_in; (void)out_size; (void)ws_size;
    const float* x      = (const float*)d_in[0];
    const float* w_qkv  = (const float*)d_in[1];
    const float* w_proj = (const float*)d_in[2];
    const float* b_proj = (const float*)d_in[3];
    float* out = (float*)d_out;

    // ws: qT | k | vT' | xh(->a_ws) | wqkvT | wprojT   (55.1 MB)
    half_t* ws     = (half_t*)d_ws;
    half_t* q_ws   = ws;                 // q transposed [bh][d][tok]
    half_t* k_ws   = ws + 6291456;
    half_t* v_ws   = ws + 2 * 6291456;   // permuted V^T (gemm epilogue)
    half_t* xh     = ws + 3 * 6291456;   // dead after gemm_qkv -> a_ws
    half_t* wqkvT  = ws + 4 * 6291456;
    half_t* wprojT = wqkvT + 1769472;
    half_t* a_ws   = xh;

    prep_kernel<<<dim3(6720), dim3(256), 0, stream>>>(x, w_qkv, w_proj, xh, wqkvT, wprojT);
    gemm_qkv<<<dim3(768), dim3(256), 0, stream>>>(xh, wqkvT, q_ws, k_ws, v_ws);
    attn_kernel<<<dim3(768), dim3(256), 0, stream>>>(q_ws, k_ws, v_ws, a_ws);
    gemm_proj<<<dim3(256), dim3(256), 0, stream>>>(a_ws, wprojT, out, b_proj);
}

// Round 4
// 198.883 us; speedup vs baseline: 1.3282x; 1.3282x over previous
//
#include <hip/hip_runtime.h>

typedef _Float16 half_t;
typedef __attribute__((ext_vector_type(4))) _Float16 half4;
typedef __attribute__((ext_vector_type(8))) _Float16 half8;
typedef __attribute__((ext_vector_type(4))) float floatx4;

#define MFMA_F16(A,B,C)  __builtin_amdgcn_mfma_f32_16x16x32_f16(A,B,C,0,0,0)

typedef __attribute__((address_space(1))) const void gvoid_t;
typedef __attribute__((address_space(3))) void svoid_t;

// async global->LDS, 16B per lane, dest = wave-uniform base + lane*16
__device__ __forceinline__ void async_copy16(const half_t* g, half_t* l) {
    __builtin_amdgcn_global_load_lds((gvoid_t*)g, (svoid_t*)l, 16, 0, 0);
}

// ============================================================================
// Prep: x fp32 -> fp16 (xh); w_qkv, w_proj fp32 -> fp16 TRANSPOSED.
// blocks: [0,6144) x-convert; [6144,6576) w_qkv 64x64 tiles; [6576,6720) w_proj
// ============================================================================
__global__ __launch_bounds__(256)
void prep_kernel(const float* __restrict__ x, const float* __restrict__ w_qkv,
                 const float* __restrict__ w_proj, half_t* __restrict__ xh,
                 half_t* __restrict__ wqkvT, half_t* __restrict__ wprojT)
{
    __shared__ half_t tile[64 * 65];
    const int id = blockIdx.x, tid = threadIdx.x;
    if (id < 6144) {
        size_t e = (size_t)id * 1024 + tid * 4;
        float4 f = *(const float4*)(x + e);
        half4 h = { (half_t)f.x, (half_t)f.y, (half_t)f.z, (half_t)f.w };
        *(half4*)(xh + e) = h;
        return;
    }
    const float* src; half_t* dst; int lds, tr0, tc0;
    if (id < 6576) { int t = id - 6144; src = w_qkv; dst = wqkvT; lds = 2304;
                     tr0 = (t / 36) * 64; tc0 = (t % 36) * 64; }
    else           { int t = id - 6576; src = w_proj; dst = wprojT; lds = 768;
                     tr0 = (t / 12) * 64; tc0 = (t % 12) * 64; }
    #pragma unroll
    for (int i = 0; i < 4; i++) {
        int e = tid + i * 256, r = e >> 4, c4 = (e & 15) << 2;
        float4 f = *(const float4*)(src + (size_t)(tr0 + r) * lds + tc0 + c4);
        tile[(c4 + 0) * 65 + r] = (half_t)f.x;
        tile[(c4 + 1) * 65 + r] = (half_t)f.y;
        tile[(c4 + 2) * 65 + r] = (half_t)f.z;
        tile[(c4 + 3) * 65 + r] = (half_t)f.w;
    }
    __syncthreads();
    #pragma unroll
    for (int i = 0; i < 4; i++) {
        int e = tid + i * 256, c = e >> 4, r4 = (e & 15) << 2;
        half4 h = { tile[c * 65 + r4], tile[c * 65 + r4 + 1],
                    tile[c * 65 + r4 + 2], tile[c * 65 + r4 + 3] };
        *(half4*)(dst + (size_t)(tc0 + c) * 768 + tr0 + r4) = h;
    }
}

// ============================================================================
// QKV GEMM v5: fine-phase pipelined (T3+T4+T5 on r1 geometry).
// Evidence: r0/r1/r2 (three schedules, same coarse phase structure) all at
// ~570 TF == the m233 2-phase ceiling; m196/m218 say the lever is the fine
// per-phase {DMA-issue || ds_read} -> barrier -> lgkm(0) -> MFMA interleave
// WITH counted vmcnt (drain-to-0 ~= 1-phase).
// Geometry: 128(M) x 192(N), BK=32, 4 waves (2x2, per-wave 64x96 = 4x6
// frags). FOUR LDS buffers (80 KB -> 2 blocks/CU), prefetch depth 2.
// Per K-step t: 4 phases, each {issue 1-2 DMA of tile t+2 || ds_read one
// C-quadrant} -> s_barrier -> lgkmcnt(0) -> setprio(1) 6 MFMA setprio(0) ->
// s_barrier. One counted s_waitcnt vmcnt(5) per step (5 DMA/wave/tile),
// placed at step end for the NEXT step's buffer; drains to 0 only at t=22.
// Epilogue contracts unchanged (q->qT scaled, k->[tok][d], v->vT' permuted).
// ============================================================================
__global__ __launch_bounds__(256, 2)
void gemm_qkv(const half_t* __restrict__ A, const half_t* __restrict__ Bt,
              half_t* __restrict__ q_ws, half_t* __restrict__ k_ws,
              half_t* __restrict__ v_ws)
{
    __shared__ half_t As[4][128 * 32];   // 4 x 8 KB
    __shared__ half_t Bs[4][192 * 32];   // 4 x 12 KB

    const int lin  = blockIdx.x;                  // 0..767
    const int xcd  = lin & 7, rest = lin >> 3;    // rest 0..95
    const int m0 = ((rest / 12) * 8 + xcd) * 128; // m-strip -> fixed XCD
    const int n0 = (rest % 12) * 192;

    const int tid  = threadIdx.x;
    const int lane = tid & 63;
    const int w    = tid >> 6;                    // 0..3
    const int wm   = w >> 1, wn = w & 1;
    const int quad = lane >> 4, l16 = lane & 15;

    // write-side inverse swizzle: lane = phys 16B chunk in a 1KB 16-row group;
    // logical chunk c: c[5:3]=lane[5:3], c2=l2^l4, c1=l1^l3, c0=l0^l2^l4
    const int b0p = (lane ^ (lane >> 2) ^ (lane >> 4)) & 1;
    const int b1p = ((lane >> 1) ^ (lane >> 3)) & 1;
    const int b2p = ((lane >> 2) ^ (lane >> 4)) & 1;
    const int row_log = ((lane >> 2) & 0xC) | ((lane >> 2) & 2) | b2p; // 0..15
    const int q_log   = (b1p << 1) | b0p;                              // 0..3

    // read-side: logical (row=l16, kchunk=quad) -> phys = c ^ (l16&7); halfs
    const int foff = ((((l16 << 2) | quad) ^ (l16 & 7)) << 3);

    const half_t* a_src0 = A  + (size_t)(m0 + (w*2+0)*16 + row_log) * 768 + q_log*8;
    const half_t* a_src1 = A  + (size_t)(m0 + (w*2+1)*16 + row_log) * 768 + q_log*8;
    const half_t* b_src0 = Bt + (size_t)(n0 + (w*3+0)*16 + row_log) * 768 + q_log*8;
    const half_t* b_src1 = Bt + (size_t)(n0 + (w*3+1)*16 + row_log) * 768 + q_log*8;
    const half_t* b_src2 = Bt + (size_t)(n0 + (w*3+2)*16 + row_log) * 768 + q_log*8;

    floatx4 acc[4][6];
    #pragma unroll
    for (int i = 0; i < 4; i++)
        #pragma unroll
        for (int j = 0; j < 6; j++) acc[i][j] = (floatx4)0.0f;

    #define DMA_A0(BUF, KO) async_copy16(a_src0 + (KO), &As[BUF][(w*2+0)*512])
    #define DMA_A1(BUF, KO) async_copy16(a_src1 + (KO), &As[BUF][(w*2+1)*512])
    #define DMA_B0(BUF, KO) async_copy16(b_src0 + (KO), &Bs[BUF][(w*3+0)*512])
    #define DMA_B1(BUF, KO) async_copy16(b_src1 + (KO), &Bs[BUF][(w*3+1)*512])
    #define DMA_B2(BUF, KO) async_copy16(b_src2 + (KO), &Bs[BUF][(w*3+2)*512])

    // prologue: tiles 0,1 in flight (10 per wave); wait to 5 => tile 0 landed
    DMA_A0(0, 0); DMA_A1(0, 0); DMA_B0(0, 0); DMA_B1(0, 0); DMA_B2(0, 0);
    DMA_A0(1, 32); DMA_A1(1, 32); DMA_B0(1, 32); DMA_B1(1, 32); DMA_B2(1, 32);
    asm volatile("s_waitcnt vmcnt(5)" ::: "memory");
    __builtin_amdgcn_s_barrier();

    #pragma unroll 1
    for (int t = 0; t < 24; ++t) {
        const int cur = t & 3;
        const int nxt = (t + 2) & 3;
        const int ko  = (t + 2) * 32;
        const bool pf = (t < 22);
        half8 a[4], b[6];

        // ---- phase 0: DMA A0,A1 || read a0,a1,b0,b1,b2 ; MFMA m01 x n012
        if (pf) { DMA_A0(nxt, ko); DMA_A1(nxt, ko); }
        a[0] = *(const half8*)(&As[cur][(wm*4 + 0) * 512 + foff]);
        a[1] = *(const half8*)(&As[cur][(wm*4 + 1) * 512 + foff]);
        b[0] = *(const half8*)(&Bs[cur][(wn*6 + 0) * 512 + foff]);
        b[1] = *(const half8*)(&Bs[cur][(wn*6 + 1) * 512 + foff]);
        b[2] = *(const half8*)(&Bs[cur][(wn*6 + 2) * 512 + foff]);
        __builtin_amdgcn_s_barrier();
        asm volatile("s_waitcnt lgkmcnt(0)" ::: "memory");
        __builtin_amdgcn_sched_barrier(0);
        __builtin_amdgcn_s_setprio(1);
        #pragma unroll
        for (int mi = 0; mi < 2; mi++)
            #pragma unroll
            for (int ni = 0; ni < 3; ni++)
                acc[mi][ni] = MFMA_F16(a[mi], b[ni], acc[mi][ni]);
        __builtin_amdgcn_s_setprio(0);
        __builtin_amdgcn_s_barrier();

        // ---- phase 1: DMA B0 || read b3,b4,b5 ; MFMA m01 x n345
        if (pf) DMA_B0(nxt, ko);
        b[3] = *(const half8*)(&Bs[cur][(wn*6 + 3) * 512 + foff]);
        b[4] = *(const half8*)(&Bs[cur][(wn*6 + 4) * 512 + foff]);
        b[5] = *(const half8*)(&Bs[cur][(wn*6 + 5) * 512 + foff]);
        __builtin_amdgcn_s_barrier();
        asm volatile("s_waitcnt lgkmcnt(0)" ::: "memory");
        __builtin_amdgcn_sched_barrier(0);
        __builtin_amdgcn_s_setprio(1);
        #pragma unroll
        for (int mi = 0; mi < 2; mi++)
            #pragma unroll
            for (int ni = 3; ni < 6; ni++)
                acc[mi][ni] = MFMA_F16(a[mi], b[ni], acc[mi][ni]);
        __builtin_amdgcn_s_setprio(0);
        __builtin_amdgcn_s_barrier();

        // ---- phase 2: DMA B1 || read a2,a3 ; MFMA m23 x n012
        if (pf) DMA_B1(nxt, ko);
        a[2] = *(const half8*)(&As[cur][(wm*4 + 2) * 512 + foff]);
        a[3] = *(const half8*)(&As[cur][(wm*4 + 3) * 512 + foff]);
        __builtin_amdgcn_s_barrier();
        asm volatile("s_waitcnt lgkmcnt(0)" ::: "memory");
        __builtin_amdgcn_sched_barrier(0);
        __builtin_amdgcn_s_setprio(1);
        #pragma unroll
        for (int mi = 2; mi < 4; mi++)
            #pragma unroll
            for (int ni = 0; ni < 3; ni++)
                acc[mi][ni] = MFMA_F16(a[mi], b[ni], acc[mi][ni]);
        __builtin_amdgcn_s_setprio(0);
        __builtin_amdgcn_s_barrier();

        // ---- phase 3: DMA B2 ; MFMA m23 x n345 (all frags held)
        if (pf) DMA_B2(nxt, ko);
        __builtin_amdgcn_s_setprio(1);
        #pragma unroll
        for (int mi = 2; mi < 4; mi++)
            #pragma unroll
            for (int ni = 3; ni < 6; ni++)
                acc[mi][ni] = MFMA_F16(a[mi], b[ni], acc[mi][ni]);
        __builtin_amdgcn_s_setprio(0);

        // step-end: counted wait for NEXT step's buffer, then publish barrier
        if (t < 22)       asm volatile("s_waitcnt vmcnt(5)" ::: "memory");
        else if (t == 22) asm volatile("s_waitcnt vmcnt(0)" ::: "memory");
        if (t < 23) __builtin_amdgcn_s_barrier();
    }
    #undef DMA_A0
    #undef DMA_A1
    #undef DMA_B0
    #undef DMA_B1
    #undef DMA_B2

    // epilogue (C layout: col = l16, row = quad*4 + reg).
    // global col = n0 + wn*96 + ni*16 + l16; 192 | 768 -> sel uniform/block.
    const int sel  = (n0 >= 1536) ? 2 : (n0 >= 768 ? 1 : 0);
    const int rem0 = n0 - sel * 768;
    const int bb   = m0 >> 10;
    const int t0   = m0 & 1023;             // block's tok base (128-aligned)
    const int rw   = wm * 64;

    if (sel == 0) {                         // q -> qT[d][tok], scaled, half4
        #pragma unroll
        for (int mi = 0; mi < 4; mi++)
            #pragma unroll
            for (int ni = 0; ni < 6; ni++) {
                int cb = rem0 + wn*96 + ni*16;
                int hh = cb >> 6;
                int d  = (cb & 63) + l16;
                size_t base = (size_t)(bb * 12 + hh) * 65536;
                int tok = t0 + rw + mi*16 + quad*4;
                half4 hv = { (half_t)(acc[mi][ni][0] * 0.125f),
                             (half_t)(acc[mi][ni][1] * 0.125f),
                             (half_t)(acc[mi][ni][2] * 0.125f),
                             (half_t)(acc[mi][ni][3] * 0.125f) };
                *(half4*)(q_ws + base + (size_t)d * 1024 + tok) = hv;
            }
    } else if (sel == 1) {                  // k -> [tok][d], scalar
        #pragma unroll
        for (int mi = 0; mi < 4; mi++)
            #pragma unroll
            for (int ni = 0; ni < 6; ni++) {
                int cb = rem0 + wn*96 + ni*16;
                int hh = cb >> 6;
                int d  = (cb & 63) + l16;
                size_t base = (size_t)(bb * 12 + hh) * 65536;
                #pragma unroll
                for (int r = 0; r < 4; r++) {
                    int tok = t0 + rw + mi*16 + quad*4 + r;
                    k_ws[base + (size_t)tok * 64 + d] = (half_t)acc[mi][ni][r];
                }
            }
    } else {                                // v -> vT'[d][tokp], half4
        #pragma unroll
        for (int mi = 0; mi < 4; mi++)
            #pragma unroll
            for (int ni = 0; ni < 6; ni++) {
                int cb = rem0 + wn*96 + ni*16;
                int hh = cb >> 6;
                int d  = (cb & 63) + l16;
                size_t base = (size_t)(bb * 12 + hh) * 65536;
                int tokb = t0 + rw + (mi >> 1) * 32;
                int tokp = tokb | (quad << 3) | ((mi & 1) << 2);
                half4 hv = { (half_t)acc[mi][ni][0], (half_t)acc[mi][ni][1],
                             (half_t)acc[mi][ni][2], (half_t)acc[mi][ni][3] };
                *(half4*)(v_ws + base + (size_t)d * 1024 + tokp) = hv;
            }
    }
}

// ============================================================================
// Proj GEMM: 128x128 tile, XCD swizzle, single-buffered (restored r0 version).
// Epilogue transposes acc tiles through LDS -> float4 stores.
// ============================================================================
__global__ __launch_bounds__(256, 2)
void gemm_proj(const half_t* __restrict__ A, const half_t* __restrict__ Bt,
               float* __restrict__ Cout, const float* __restrict__ bias)
{
    __shared__ half_t As[128 * 64];
    __shared__ half_t Bs[128 * 64];

    const int lin  = blockIdx.x;                 // 0..383
    const int xcd  = lin & 7, rest = lin >> 3;
    const int m0 = ((rest / 6) * 8 + xcd) * 128;
    const int n0 = (rest % 6) * 128;

    const int tid  = threadIdx.x;
    const int lane = tid & 63;
    const int w    = tid >> 6;
    const int wm   = w >> 1, wn = w & 1;
    const int quad = lane >> 4, l16 = lane & 15;
    const int lrow = lane >> 3;
    const int lcc  = (lane & 7) ^ lrow;
    const int xsw  = l16 & 7;

    const half_t* Ag = A  + (size_t)(m0 + w * 32 + lrow) * 768 + lcc * 8;
    const half_t* Bg = Bt + (size_t)(n0 + w * 32 + lrow) * 768 + lcc * 8;

    floatx4 acc[4][4];
    #pragma unroll
    for (int i = 0; i < 4; i++)
        #pragma unroll
        for (int j = 0; j < 4; j++) acc[i][j] = (floatx4)0.0f;

    for (int k0 = 0; k0 < 768; k0 += 64) {
        #pragma unroll
        for (int i = 0; i < 4; i++) {
            async_copy16(Ag + (size_t)(i * 8) * 768 + k0, As + (w * 4 + i) * 512);
            async_copy16(Bg + (size_t)(i * 8) * 768 + k0, Bs + (w * 4 + i) * 512);
        }
        __syncthreads();

        #pragma unroll
        for (int ks = 0; ks < 2; ks++) {
            const int co = (((ks << 2) + quad) ^ xsw) * 8;
            half8 a[4], b[4];
            #pragma unroll
            for (int mi = 0; mi < 4; mi++)
                a[mi] = *(const half8*)(As + (wm * 64 + mi * 16 + l16) * 64 + co);
            #pragma unroll
            for (int ni = 0; ni < 4; ni++)
                b[ni] = *(const half8*)(Bs + (wn * 64 + ni * 16 + l16) * 64 + co);
            #pragma unroll
            for (int mi = 0; mi < 4; mi++)
                #pragma unroll
                for (int ni = 0; ni < 4; ni++)
                    acc[mi][ni] = MFMA_F16(a[mi], b[ni], acc[mi][ni]);
        }
        __syncthreads();
    }

    // epilogue: per-wave LDS transpose (rows padded to 72 f32: 288B, 16B-aligned)
    float bias_v[4];
    #pragma unroll
    for (int ni = 0; ni < 4; ni++)
        bias_v[ni] = bias[n0 + wn * 64 + ni * 16 + l16];
    float* scratch = (w < 2 ? (float*)As : (float*)Bs) + (w & 1) * 1152;
    #pragma unroll
    for (int mi = 0; mi < 4; mi++) {
        #pragma unroll
        for (int ni = 0; ni < 4; ni++)
            #pragma unroll
            for (int r = 0; r < 4; r++)
                scratch[(quad * 4 + r) * 72 + ni * 16 + l16] =
                    acc[mi][ni][r] + bias_v[ni];
        #pragma unroll
        for (int i = 0; i < 4; i++) {
            int f = quad + i * 4;           // float4 index 0..15
            float4 v4 = *(const float4*)(scratch + l16 * 72 + f * 4);
            int gm = m0 + wm * 64 + mi * 16 + l16;
            *(float4*)(Cout + (size_t)gm * 768 + n0 + wn * 64 + f * 4) = v4;
        }
    }
}

// ============================================================================
// Flash attention v5: S^T = K.Q^T -> P in registers in PV-A layout; vT'
// key-permuted -> full-rate 16x16x32 PV. Q arrives TRANSPOSED (qT[d][tok])
// -> staged via global_load_lds into Qs, frags built by one-time scalar
// ds_reads. XCD swizzle; K/V double-buffered; no max subtraction.
// LDS: 16+16+16 KB = 48 KB -> 3 blocks/CU.
// ============================================================================
__global__ __launch_bounds__(256, 3)
void attn_kernel(const half_t* __restrict__ qT, const half_t* __restrict__ k,
                 const half_t* __restrict__ vT, half_t* __restrict__ a_ws)
{
    __shared__ __align__(16) half_t Kb[2][4096];
    __shared__ __align__(16) half_t Vb[2][4096];
    __shared__ __align__(16) half_t Qs[64 * 128];

    const int lin  = blockIdx.x;
    const int xcd  = lin & 7, rest = lin >> 3;
    const int qc   = rest & 7;                    // 0..7 (128-row q chunk)
    const int bh   = (rest >> 3) * 8 + xcd;       // 0..95; same bh -> same XCD

    const int tid  = threadIdx.x;
    const int lane = tid & 63;
    const int w    = tid >> 6;
    const int quad = lane >> 4, l16 = lane & 15;

    const half_t* qg = qT + (size_t)bh * 65536;   // [d][tok]
    const half_t* kg = k  + (size_t)bh * 65536;   // [key][d]
    const half_t* vg = vT + (size_t)bh * 65536;   // [d][tok'] permuted

    const int srow = lane >> 3;              // 0..7
    const int sch  = (lane & 7) ^ srow;      // swizzled chunk for deposit

    // stage Q^T tile [64 d][128 toks] (rows of 128, no swizzle: scalar reads)
    #pragma unroll
    for (int j = 0; j < 4; j++) {
        int d0 = w * 16 + j * 4;
        async_copy16(qg + (size_t)(d0 + (lane >> 4)) * 1024 + qc * 128 + (lane & 15) * 8,
                     &Qs[d0 * 128]);
    }
    // prologue prefetch: K/V tile 0 -> buffer 0
    #pragma unroll
    for (int j = 0; j < 2; j++) {
        int row = j * 32 + w * 8;
        async_copy16(kg + (size_t)(row + srow) * 64 + sch * 8, &Kb[0][row * 64]);
        async_copy16(vg + (size_t)(row + srow) * 1024 + sch * 8, &Vb[0][row * 64]);
    }
    __syncthreads();   // drains Q stage (and tile 0)

    // Q fragments (B-operand of S^T MFMA): B[n=query l16][k=d quad*8+j]
    half8 qf[2][2];
    #pragma unroll
    for (int T = 0; T < 2; T++)
        #pragma unroll
        for (int ks = 0; ks < 2; ks++)
            #pragma unroll
            for (int j = 0; j < 8; j++)
                qf[T][ks][j] = Qs[(ks * 32 + quad * 8 + j) * 128
                                  + T * 64 + w * 16 + l16];

    floatx4 acc_o[2][4];
    floatx4 lacc[2];
    #pragma unroll
    for (int T = 0; T < 2; T++) {
        lacc[T] = (floatx4)0.0f;
        #pragma unroll
        for (int dt = 0; dt < 4; dt++) acc_o[T][dt] = (floatx4)0.0f;
    }

    const int xsw = l16 & 7;
    const half8 vone = { (half_t)1.0f, (half_t)1.0f, (half_t)1.0f, (half_t)1.0f,
                         (half_t)1.0f, (half_t)1.0f, (half_t)1.0f, (half_t)1.0f };

    for (int kt = 0; kt < 16; kt++) {
        const int cb = kt & 1;
        __syncthreads();               // drains prefetch of tile kt
        if (kt < 15) {                 // prefetch tile kt+1 into other buffer
            #pragma unroll
            for (int j = 0; j < 2; j++) {
                int row = j * 32 + w * 8;
                async_copy16(kg + (size_t)((kt + 1) * 64 + row + srow) * 64 + sch * 8,
                             &Kb[cb ^ 1][row * 64]);
                async_copy16(vg + (size_t)(row + srow) * 1024 + (kt + 1) * 64 + sch * 8,
                             &Vb[cb ^ 1][row * 64]);
            }
        }
        const half_t* Kc = Kb[cb];
        const half_t* Vc = Vb[cb];

        // S^T = K . Q^T : A-frag = K[key=l16][d=quad*8+j] (LDS), B-frag = qf.
        // C: lane holds S[query=l16][key = mt*16 + quad*4 + r].
        floatx4 sc[2][4];
        #pragma unroll
        for (int T = 0; T < 2; T++)
            #pragma unroll
            for (int mt = 0; mt < 4; mt++) sc[T][mt] = (floatx4)0.0f;
        #pragma unroll
        for (int ks = 0; ks < 2; ks++)
            #pragma unroll
            for (int mt = 0; mt < 4; mt++) {
                half8 kf = *(const half8*)(Kc + (mt * 16 + l16) * 64
                                              + (((ks << 2) + quad) ^ xsw) * 8);
                sc[0][mt] = MFMA_F16(kf, qf[0][ks], sc[0][mt]);
                sc[1][mt] = MFMA_F16(kf, qf[1][ks], sc[1][mt]);
            }

        // P = exp(S), packed per 32-key group into 16x16x32 A-frags
        half8 pa[2][2];   // [T][group]
        #pragma unroll
        for (int T = 0; T < 2; T++)
            #pragma unroll
            for (int g = 0; g < 2; g++) {
                half8 ph;
                #pragma unroll
                for (int r = 0; r < 4; r++) ph[r]     = (half_t)__expf(sc[T][2 * g][r]);
                #pragma unroll
                for (int r = 0; r < 4; r++) ph[4 + r] = (half_t)__expf(sc[T][2 * g + 1][r]);
                pa[T][g] = ph;
            }

        // l += P.1 and O += P.V' (full-rate 16x16x32, b128 V reads)
        #pragma unroll
        for (int g = 0; g < 2; g++) {
            lacc[0] = MFMA_F16(pa[0][g], vone, lacc[0]);
            lacc[1] = MFMA_F16(pa[1][g], vone, lacc[1]);
            #pragma unroll
            for (int dt = 0; dt < 4; dt++) {
                half8 vb = *(const half8*)(Vc + (dt * 16 + l16) * 64
                                              + ((((g << 2) + quad) ^ xsw) << 3));
                acc_o[0][dt] = MFMA_F16(pa[0][g], vb, acc_o[0][dt]);
                acc_o[1][dt] = MFMA_F16(pa[1][g], vb, acc_o[1][dt]);
            }
        }
    }

    // epilogue: a_ws[(b*1024+n)*768 + h*64 + d]; O C-layout row=query quad*4+r
    const int b = bh / 12, h = bh - (bh / 12) * 12;
    #pragma unroll
    for (int T = 0; T < 2; T++)
        #pragma unroll
        for (int r = 0; r < 4; r++) {
            float inv = 1.0f / lacc[T][r];
            int n = qc * 128 + T * 64 + w * 16 + quad * 4 + r;
            half_t* op = a_ws + ((size_t)(b * 1024 + n)) * 768 + h * 64;
            #pragma unroll
            for (int dt = 0; dt < 4; dt++)
                op[dt * 16 + l16] = (half_t)(acc_o[T][dt][r] * inv);
        }
}

extern "C" void kernel_launch(void* const* d_in, const int* in_sizes, int n_in,
                              void* d_out, int out_size, void* d_ws, size_t ws_size,
                              hipStream_t stream)
{
    (void)in_sizes; (void)n_in; (void)out_size; (void)ws_size;
    const float* x      = (const float*)d_in[0];
    const float* w_qkv  = (const float*)d_in[1];
    const float* w_proj = (const float*)d_in[2];
    const float* b_proj = (const float*)d_in[3];
    float* out = (float*)d_out;

    // ws: qT | k | vT' | xh(->a_ws) | wqkvT | wprojT   (55.1 MB)
    half_t* ws     = (half_t*)d_ws;
    half_t* q_ws   = ws;                 // q transposed [bh][d][tok]
    half_t* k_ws   = ws + 6291456;
    half_t* v_ws   = ws + 2 * 6291456;   // permuted V^T (gemm epilogue)
    half_t* xh     = ws + 3 * 6291456;   // dead after gemm_qkv -> a_ws
    half_t* wqkvT  = ws + 4 * 6291456;
    half_t* wprojT = wqkvT + 1769472;
    half_t* a_ws   = xh;

    prep_kernel<<<dim3(6720), dim3(256), 0, stream>>>(x, w_qkv, w_proj, xh, wqkvT, wprojT);
    gemm_qkv<<<dim3(768), dim3(256), 0, stream>>>(xh, wqkvT, q_ws, k_ws, v_ws);
    attn_kernel<<<dim3(768), dim3(256), 0, stream>>>(q_ws, k_ws, v_ws, a_ws);
    gemm_proj<<<dim3(384), dim3(256), 0, stream>>>(a_ws, wprojT, out, b_proj);
}

// Round 5
// 177.736 us; speedup vs baseline: 1.4863x; 1.1190x over previous
//
#include <hip/hip_runtime.h>

typedef _Float16 half_t;
typedef __attribute__((ext_vector_type(4))) _Float16 half4;
typedef __attribute__((ext_vector_type(8))) _Float16 half8;
typedef __attribute__((ext_vector_type(4))) float floatx4;

#define MFMA_F16(A,B,C)  __builtin_amdgcn_mfma_f32_16x16x32_f16(A,B,C,0,0,0)

typedef __attribute__((address_space(1))) const void gvoid_t;
typedef __attribute__((address_space(3))) void svoid_t;

// async global->LDS, 16B per lane, dest = wave-uniform base + lane*16
__device__ __forceinline__ void async_copy16(const half_t* g, half_t* l) {
    __builtin_amdgcn_global_load_lds((gvoid_t*)g, (svoid_t*)l, 16, 0, 0);
}

// ============================================================================
// Prep: x fp32 -> fp16 (xh); w_qkv, w_proj fp32 -> fp16 TRANSPOSED.
// blocks: [0,6144) x-convert; [6144,6576) w_qkv 64x64 tiles; [6576,6720) w_proj
// ============================================================================
__global__ __launch_bounds__(256)
void prep_kernel(const float* __restrict__ x, const float* __restrict__ w_qkv,
                 const float* __restrict__ w_proj, half_t* __restrict__ xh,
                 half_t* __restrict__ wqkvT, half_t* __restrict__ wprojT)
{
    __shared__ half_t tile[64 * 65];
    const int id = blockIdx.x, tid = threadIdx.x;
    if (id < 6144) {
        size_t e = (size_t)id * 1024 + tid * 4;
        float4 f = *(const float4*)(x + e);
        half4 h = { (half_t)f.x, (half_t)f.y, (half_t)f.z, (half_t)f.w };
        *(half4*)(xh + e) = h;
        return;
    }
    const float* src; half_t* dst; int lds, tr0, tc0;
    if (id < 6576) { int t = id - 6144; src = w_qkv; dst = wqkvT; lds = 2304;
                     tr0 = (t / 36) * 64; tc0 = (t % 36) * 64; }
    else           { int t = id - 6576; src = w_proj; dst = wprojT; lds = 768;
                     tr0 = (t / 12) * 64; tc0 = (t % 12) * 64; }
    #pragma unroll
    for (int i = 0; i < 4; i++) {
        int e = tid + i * 256, r = e >> 4, c4 = (e & 15) << 2;
        float4 f = *(const float4*)(src + (size_t)(tr0 + r) * lds + tc0 + c4);
        tile[(c4 + 0) * 65 + r] = (half_t)f.x;
        tile[(c4 + 1) * 65 + r] = (half_t)f.y;
        tile[(c4 + 2) * 65 + r] = (half_t)f.z;
        tile[(c4 + 3) * 65 + r] = (half_t)f.w;
    }
    __syncthreads();
    #pragma unroll
    for (int i = 0; i < 4; i++) {
        int e = tid + i * 256, c = e >> 4, r4 = (e & 15) << 2;
        half4 h = { tile[c * 65 + r4], tile[c * 65 + r4 + 1],
                    tile[c * 65 + r4 + 2], tile[c * 65 + r4 + 3] };
        *(half4*)(dst + (size_t)(tc0 + c) * 768 + tr0 + r4) = h;
    }
}

// ============================================================================
// QKV GEMM v6: BIG TILE to cut staged bytes (the measured ~12 B/cy/CU DMA
// throughput bound: r0 340MB/49.5us, r1/r2 377MB/51us, r3 2x bytes -> 2.4x
// slower, m97 itself = 11 B/cy/CU). Traffic = 12.6MB*(2304/BN) +
// 3.5MB*(8192/BM): (128,192)=375MB -> (256,288)=213MB (-43%).
// Grid 32x8 = 256 blocks = EXACTLY 1/CU. 512 threads = 8 waves (4M x 2N),
// per-wave 64x144 = 4x9 frags (144 acc VGPR, ~216 total, 2 waves/SIMD).
// BK=32, double-buffered LDS 68 KB (static >64KB proven OK: r2 ran 80KB).
// Schedule = r1's proven shape: stage(t+1 -> other buf) -> compute(t) ->
// __syncthreads (implicit vmcnt(0) drain; t+1 latency overlaps compute).
// Staging/read machinery identical to r1 (16-row 512-half chunks, inverse
// XOR swizzle on the global source, foff on reads).
// Epilogue: per-frag col cb = n0+wn*144+ni*16 is 16-aligned => sel (q/k/v),
// head, and d0 are frag-uniform. Same q/k/v layout contracts as before.
// ============================================================================
__global__ __launch_bounds__(512, 2)
void gemm_qkv(const half_t* __restrict__ A, const half_t* __restrict__ Bt,
              half_t* __restrict__ q_ws, half_t* __restrict__ k_ws,
              half_t* __restrict__ v_ws)
{
    __shared__ half_t As[2][256 * 32];   // 2 x 16 KB
    __shared__ half_t Bs[2][288 * 32];   // 2 x 18 KB

    const int lin  = blockIdx.x;                  // 0..255
    const int xcd  = lin & 7, rest = lin >> 3;    // rest 0..31
    const int m0 = ((rest >> 3) * 8 + xcd) * 256; // 32 m-strips; same-m -> XCD
    const int n0 = (rest & 7) * 288;              // 8 n-strips

    const int tid  = threadIdx.x;
    const int lane = tid & 63;
    const int w    = tid >> 6;                    // 0..7
    const int wm   = w >> 1, wn = w & 1;          // 4M x 2N wave grid
    const int quad = lane >> 4, l16 = lane & 15;

    // write-side inverse swizzle (r1 machinery): lane -> (row_log, q_log)
    // within a 512-half chunk (16 rows x 32 halfs = 4 x 16B sub-chunks/row)
    const int b0p = (lane ^ (lane >> 2) ^ (lane >> 4)) & 1;
    const int b1p = ((lane >> 1) ^ (lane >> 3)) & 1;
    const int b2p = ((lane >> 2) ^ (lane >> 4)) & 1;
    const int row_log = ((lane >> 2) & 0xC) | ((lane >> 2) & 2) | b2p; // 0..15
    const int q_log   = (b1p << 1) | b0p;                              // 0..3

    // read-side: logical (row=l16, kchunk=quad) -> phys offset in halfs
    const int foff = ((((l16 << 2) | quad) ^ (l16 & 7)) << 3);

    // staging sources (chunk c covers rows base+c*16): per-wave chunk list:
    //   A (16 chunks): {2w, 2w+1};  B (18 chunks): {2w, 2w+1} + (w<2: 16+w)
    const half_t* aBase = A  + (size_t)(m0 + row_log) * 768 + q_log * 8;
    const half_t* bBase = Bt + (size_t)(n0 + row_log) * 768 + q_log * 8;

    floatx4 acc[4][9];
    #pragma unroll
    for (int i = 0; i < 4; i++)
        #pragma unroll
        for (int j = 0; j < 9; j++) acc[i][j] = (floatx4)0.0f;

    #define STAGE(BUF, KO)                                                     \
        do {                                                                   \
            _Pragma("unroll")                                                  \
            for (int c = 0; c < 2; c++) {                                      \
                async_copy16(aBase + (size_t)((w*2 + c) * 16) * 768 + (KO),    \
                             &As[BUF][(w*2 + c) * 512]);                       \
                async_copy16(bBase + (size_t)((w*2 + c) * 16) * 768 + (KO),    \
                             &Bs[BUF][(w*2 + c) * 512]);                       \
            }                                                                  \
            if (w < 2)                                                         \
                async_copy16(bBase + (size_t)((16 + w) * 16) * 768 + (KO),     \
                             &Bs[BUF][(16 + w) * 512]);                        \
        } while (0)

    STAGE(0, 0);
    __syncthreads();

    #pragma unroll 1
    for (int t = 0; t < 24; ++t) {
        const int cur = t & 1;
        if (t < 23) STAGE(cur ^ 1, (t + 1) * 32);

        half8 a[4], b[9];
        #pragma unroll
        for (int mi = 0; mi < 4; mi++)
            a[mi] = *(const half8*)(&As[cur][(wm*4 + mi) * 512 + foff]);
        #pragma unroll
        for (int ni = 0; ni < 9; ni++)
            b[ni] = *(const half8*)(&Bs[cur][(wn*9 + ni) * 512 + foff]);
        #pragma unroll
        for (int mi = 0; mi < 4; mi++)
            #pragma unroll
            for (int ni = 0; ni < 9; ni++)
                acc[mi][ni] = MFMA_F16(a[mi], b[ni], acc[mi][ni]);

        __syncthreads();   // drains t+1 prefetch after compute overlap
    }
    #undef STAGE

    // epilogue (C layout: col = l16, row = quad*4 + reg). Per-frag col base
    // cb = n0 + wn*144 + ni*16 is 16-aligned -> sel/head/d0 frag-uniform.
    const int bb  = (m0 + wm * 64) >> 10;
    const int t0w = (m0 + wm * 64) & 1023;   // wave tok base (64-aligned)

    #pragma unroll
    for (int ni = 0; ni < 9; ni++) {
        const int cb  = n0 + wn * 144 + ni * 16;
        const int sel = (cb >= 1536) ? 2 : (cb >= 768 ? 1 : 0);
        const int rem = cb - sel * 768;
        const int hh  = rem >> 6;
        const int d   = (rem & 63) + l16;
        const size_t base = (size_t)(bb * 12 + hh) * 65536;

        if (sel == 0) {                     // q -> qT[d][tok], scaled, half4
            #pragma unroll
            for (int mi = 0; mi < 4; mi++) {
                int tok = t0w + mi * 16 + quad * 4;
                half4 hv = { (half_t)(acc[mi][ni][0] * 0.125f),
                             (half_t)(acc[mi][ni][1] * 0.125f),
                             (half_t)(acc[mi][ni][2] * 0.125f),
                             (half_t)(acc[mi][ni][3] * 0.125f) };
                *(half4*)(q_ws + base + (size_t)d * 1024 + tok) = hv;
            }
        } else if (sel == 1) {              // k -> [tok][d], scalar
            #pragma unroll
            for (int mi = 0; mi < 4; mi++)
                #pragma unroll
                for (int r = 0; r < 4; r++) {
                    int tok = t0w + mi * 16 + quad * 4 + r;
                    k_ws[base + (size_t)tok * 64 + d] = (half_t)acc[mi][ni][r];
                }
        } else {                            // v -> vT'[d][tokp], half4
            #pragma unroll
            for (int mi = 0; mi < 4; mi++) {
                int tokb = t0w + (mi >> 1) * 32;
                int tokp = tokb | (quad << 3) | ((mi & 1) << 2);
                half4 hv = { (half_t)acc[mi][ni][0], (half_t)acc[mi][ni][1],
                             (half_t)acc[mi][ni][2], (half_t)acc[mi][ni][3] };
                *(half4*)(v_ws + base + (size_t)d * 1024 + tokp) = hv;
            }
        }
    }
}

// ============================================================================
// Proj GEMM: 128x128 tile, XCD swizzle, single-buffered (r0 version).
// Epilogue transposes acc tiles through LDS -> float4 stores.
// ============================================================================
__global__ __launch_bounds__(256, 2)
void gemm_proj(const half_t* __restrict__ A, const half_t* __restrict__ Bt,
               float* __restrict__ Cout, const float* __restrict__ bias)
{
    __shared__ half_t As[128 * 64];
    __shared__ half_t Bs[128 * 64];

    const int lin  = blockIdx.x;                 // 0..383
    const int xcd  = lin & 7, rest = lin >> 3;
    const int m0 = ((rest / 6) * 8 + xcd) * 128;
    const int n0 = (rest % 6) * 128;

    const int tid  = threadIdx.x;
    const int lane = tid & 63;
    const int w    = tid >> 6;
    const int wm   = w >> 1, wn = w & 1;
    const int quad = lane >> 4, l16 = lane & 15;
    const int lrow = lane >> 3;
    const int lcc  = (lane & 7) ^ lrow;
    const int xsw  = l16 & 7;

    const half_t* Ag = A  + (size_t)(m0 + w * 32 + lrow) * 768 + lcc * 8;
    const half_t* Bg = Bt + (size_t)(n0 + w * 32 + lrow) * 768 + lcc * 8;

    floatx4 acc[4][4];
    #pragma unroll
    for (int i = 0; i < 4; i++)
        #pragma unroll
        for (int j = 0; j < 4; j++) acc[i][j] = (floatx4)0.0f;

    for (int k0 = 0; k0 < 768; k0 += 64) {
        #pragma unroll
        for (int i = 0; i < 4; i++) {
            async_copy16(Ag + (size_t)(i * 8) * 768 + k0, As + (w * 4 + i) * 512);
            async_copy16(Bg + (size_t)(i * 8) * 768 + k0, Bs + (w * 4 + i) * 512);
        }
        __syncthreads();

        #pragma unroll
        for (int ks = 0; ks < 2; ks++) {
            const int co = (((ks << 2) + quad) ^ xsw) * 8;
            half8 a[4], b[4];
            #pragma unroll
            for (int mi = 0; mi < 4; mi++)
                a[mi] = *(const half8*)(As + (wm * 64 + mi * 16 + l16) * 64 + co);
            #pragma unroll
            for (int ni = 0; ni < 4; ni++)
                b[ni] = *(const half8*)(Bs + (wn * 64 + ni * 16 + l16) * 64 + co);
            #pragma unroll
            for (int mi = 0; mi < 4; mi++)
                #pragma unroll
                for (int ni = 0; ni < 4; ni++)
                    acc[mi][ni] = MFMA_F16(a[mi], b[ni], acc[mi][ni]);
        }
        __syncthreads();
    }

    // epilogue: per-wave LDS transpose (rows padded to 72 f32: 288B, 16B-aligned)
    float bias_v[4];
    #pragma unroll
    for (int ni = 0; ni < 4; ni++)
        bias_v[ni] = bias[n0 + wn * 64 + ni * 16 + l16];
    float* scratch = (w < 2 ? (float*)As : (float*)Bs) + (w & 1) * 1152;
    #pragma unroll
    for (int mi = 0; mi < 4; mi++) {
        #pragma unroll
        for (int ni = 0; ni < 4; ni++)
            #pragma unroll
            for (int r = 0; r < 4; r++)
                scratch[(quad * 4 + r) * 72 + ni * 16 + l16] =
                    acc[mi][ni][r] + bias_v[ni];
        #pragma unroll
        for (int i = 0; i < 4; i++) {
            int f = quad + i * 4;           // float4 index 0..15
            float4 v4 = *(const float4*)(scratch + l16 * 72 + f * 4);
            int gm = m0 + wm * 64 + mi * 16 + l16;
            *(float4*)(Cout + (size_t)gm * 768 + n0 + wn * 64 + f * 4) = v4;
        }
    }
}

// ============================================================================
// Flash attention v5: S^T = K.Q^T -> P in registers in PV-A layout; vT'
// key-permuted -> full-rate 16x16x32 PV. Q arrives TRANSPOSED (qT[d][tok])
// -> staged via global_load_lds into Qs, frags built by one-time scalar
// ds_reads. XCD swizzle; K/V double-buffered; no max subtraction.
// LDS: 16+16+16 KB = 48 KB -> 3 blocks/CU.
// ============================================================================
__global__ __launch_bounds__(256, 3)
void attn_kernel(const half_t* __restrict__ qT, const half_t* __restrict__ k,
                 const half_t* __restrict__ vT, half_t* __restrict__ a_ws)
{
    __shared__ __align__(16) half_t Kb[2][4096];
    __shared__ __align__(16) half_t Vb[2][4096];
    __shared__ __align__(16) half_t Qs[64 * 128];

    const int lin  = blockIdx.x;
    const int xcd  = lin & 7, rest = lin >> 3;
    const int qc   = rest & 7;                    // 0..7 (128-row q chunk)
    const int bh   = (rest >> 3) * 8 + xcd;       // 0..95; same bh -> same XCD

    const int tid  = threadIdx.x;
    const int lane = tid & 63;
    const int w    = tid >> 6;
    const int quad = lane >> 4, l16 = lane & 15;

    const half_t* qg = qT + (size_t)bh * 65536;   // [d][tok]
    const half_t* kg = k  + (size_t)bh * 65536;   // [key][d]
    const half_t* vg = vT + (size_t)bh * 65536;   // [d][tok'] permuted

    const int srow = lane >> 3;              // 0..7
    const int sch  = (lane & 7) ^ srow;      // swizzled chunk for deposit

    // stage Q^T tile [64 d][128 toks] (rows of 128, no swizzle: scalar reads)
    #pragma unroll
    for (int j = 0; j < 4; j++) {
        int d0 = w * 16 + j * 4;
        async_copy16(qg + (size_t)(d0 + (lane >> 4)) * 1024 + qc * 128 + (lane & 15) * 8,
                     &Qs[d0 * 128]);
    }
    // prologue prefetch: K/V tile 0 -> buffer 0
    #pragma unroll
    for (int j = 0; j < 2; j++) {
        int row = j * 32 + w * 8;
        async_copy16(kg + (size_t)(row + srow) * 64 + sch * 8, &Kb[0][row * 64]);
        async_copy16(vg + (size_t)(row + srow) * 1024 + sch * 8, &Vb[0][row * 64]);
    }
    __syncthreads();   // drains Q stage (and tile 0)

    // Q fragments (B-operand of S^T MFMA): B[n=query l16][k=d quad*8+j]
    half8 qf[2][2];
    #pragma unroll
    for (int T = 0; T < 2; T++)
        #pragma unroll
        for (int ks = 0; ks < 2; ks++)
            #pragma unroll
            for (int j = 0; j < 8; j++)
                qf[T][ks][j] = Qs[(ks * 32 + quad * 8 + j) * 128
                                  + T * 64 + w * 16 + l16];

    floatx4 acc_o[2][4];
    floatx4 lacc[2];
    #pragma unroll
    for (int T = 0; T < 2; T++) {
        lacc[T] = (floatx4)0.0f;
        #pragma unroll
        for (int dt = 0; dt < 4; dt++) acc_o[T][dt] = (floatx4)0.0f;
    }

    const int xsw = l16 & 7;
    const half8 vone = { (half_t)1.0f, (half_t)1.0f, (half_t)1.0f, (half_t)1.0f,
                         (half_t)1.0f, (half_t)1.0f, (half_t)1.0f, (half_t)1.0f };

    for (int kt = 0; kt < 16; kt++) {
        const int cb = kt & 1;
        __syncthreads();               // drains prefetch of tile kt
        if (kt < 15) {                 // prefetch tile kt+1 into other buffer
            #pragma unroll
            for (int j = 0; j < 2; j++) {
                int row = j * 32 + w * 8;
                async_copy16(kg + (size_t)((kt + 1) * 64 + row + srow) * 64 + sch * 8,
                             &Kb[cb ^ 1][row * 64]);
                async_copy16(vg + (size_t)(row + srow) * 1024 + (kt + 1) * 64 + sch * 8,
                             &Vb[cb ^ 1][row * 64]);
            }
        }
        const half_t* Kc = Kb[cb];
        const half_t* Vc = Vb[cb];

        // S^T = K . Q^T : A-frag = K[key=l16][d=quad*8+j] (LDS), B-frag = qf.
        // C: lane holds S[query=l16][key = mt*16 + quad*4 + r].
        floatx4 sc[2][4];
        #pragma unroll
        for (int T = 0; T < 2; T++)
            #pragma unroll
            for (int mt = 0; mt < 4; mt++) sc[T][mt] = (floatx4)0.0f;
        #pragma unroll
        for (int ks = 0; ks < 2; ks++)
            #pragma unroll
            for (int mt = 0; mt < 4; mt++) {
                half8 kf = *(const half8*)(Kc + (mt * 16 + l16) * 64
                                              + (((ks << 2) + quad) ^ xsw) * 8);
                sc[0][mt] = MFMA_F16(kf, qf[0][ks], sc[0][mt]);
                sc[1][mt] = MFMA_F16(kf, qf[1][ks], sc[1][mt]);
            }

        // P = exp(S), packed per 32-key group into 16x16x32 A-frags
        half8 pa[2][2];   // [T][group]
        #pragma unroll
        for (int T = 0; T < 2; T++)
            #pragma unroll
            for (int g = 0; g < 2; g++) {
                half8 ph;
                #pragma unroll
                for (int r = 0; r < 4; r++) ph[r]     = (half_t)__expf(sc[T][2 * g][r]);
                #pragma unroll
                for (int r = 0; r < 4; r++) ph[4 + r] = (half_t)__expf(sc[T][2 * g + 1][r]);
                pa[T][g] = ph;
            }

        // l += P.1 and O += P.V' (full-rate 16x16x32, b128 V reads)
        #pragma unroll
        for (int g = 0; g < 2; g++) {
            lacc[0] = MFMA_F16(pa[0][g], vone, lacc[0]);
            lacc[1] = MFMA_F16(pa[1][g], vone, lacc[1]);
            #pragma unroll
            for (int dt = 0; dt < 4; dt++) {
                half8 vb = *(const half8*)(Vc + (dt * 16 + l16) * 64
                                              + ((((g << 2) + quad) ^ xsw) << 3));
                acc_o[0][dt] = MFMA_F16(pa[0][g], vb, acc_o[0][dt]);
                acc_o[1][dt] = MFMA_F16(pa[1][g], vb, acc_o[1][dt]);
            }
        }
    }

    // epilogue: a_ws[(b*1024+n)*768 + h*64 + d]; O C-layout row=query quad*4+r
    const int b = bh / 12, h = bh - (bh / 12) * 12;
    #pragma unroll
    for (int T = 0; T < 2; T++)
        #pragma unroll
        for (int r = 0; r < 4; r++) {
            float inv = 1.0f / lacc[T][r];
            int n = qc * 128 + T * 64 + w * 16 + quad * 4 + r;
            half_t* op = a_ws + ((size_t)(b * 1024 + n)) * 768 + h * 64;
            #pragma unroll
            for (int dt = 0; dt < 4; dt++)
                op[dt * 16 + l16] = (half_t)(acc_o[T][dt][r] * inv);
        }
}

extern "C" void kernel_launch(void* const* d_in, const int* in_sizes, int n_in,
                              void* d_out, int out_size, void* d_ws, size_t ws_size,
                              hipStream_t stream)
{
    (void)in_sizes; (void)n_in; (void)out_size; (void)ws_size;
    const float* x      = (const float*)d_in[0];
    const float* w_qkv  = (const float*)d_in[1];
    const float* w_proj = (const float*)d_in[2];
    const float* b_proj = (const float*)d_in[3];
    float* out = (float*)d_out;

    // ws: qT | k | vT' | xh(->a_ws) | wqkvT | wprojT   (55.1 MB)
    half_t* ws     = (half_t*)d_ws;
    half_t* q_ws   = ws;                 // q transposed [bh][d][tok]
    half_t* k_ws   = ws + 6291456;
    half_t* v_ws   = ws + 2 * 6291456;   // permuted V^T (gemm epilogue)
    half_t* xh     = ws + 3 * 6291456;   // dead after gemm_qkv -> a_ws
    half_t* wqkvT  = ws + 4 * 6291456;
    half_t* wprojT = wqkvT + 1769472;
    half_t* a_ws   = xh;

    prep_kernel<<<dim3(6720), dim3(256), 0, stream>>>(x, w_qkv, w_proj, xh, wqkvT, wprojT);
    gemm_qkv<<<dim3(256), dim3(512), 0, stream>>>(xh, wqkvT, q_ws, k_ws, v_ws);
    attn_kernel<<<dim3(768), dim3(256), 0, stream>>>(q_ws, k_ws, v_ws, a_ws);
    gemm_proj<<<dim3(384), dim3(256), 0, stream>>>(a_ws, wprojT, out, b_proj);
}